// Round 1
// baseline (833.310 us; speedup 1.0000x reference)
//
#include <hip/hip_runtime.h>
#include <math.h>

// RBF mixture: out[i] = sum_m w_m * exp(-(x_i-mu_m)^T C_m (x_i-mu_m)), C_m = G_m G_m^T
// N=32768, M=2048, D=32. Strategy: bf16 MFMA screening GEMM over expanded form
// D~ = x^T C x - 2 x^T (C mu) + mu^T C mu  (K = 1024 + 32 + 2, padded to 1088),
// then exact fp32 recompute ||G^T (x-mu)||^2 only for pairs with D~ < SCREEN
// (exp(-D) underflows fp32 for D > ~104; screening margin is huge).

#define NN 32768
#define MM 2048
#define DDIM 32
#define KPAD 1088          // 17 * 64
#define ASTRIDE 72         // 64 + 8 pad (bf16 elems); 144 B rows, 16B-aligned, 2-way-free banks
#define SCREEN 256.0f

typedef __attribute__((ext_vector_type(8))) short short8;
typedef __attribute__((ext_vector_type(4))) float floatx4;

__device__ __forceinline__ unsigned int to_bf16(float f) {
  union { float f; unsigned int u; } x; x.f = f;
  return (x.u + 0x7fffu + ((x.u >> 16) & 1u)) >> 16;   // RNE, finite inputs only
}

// ---------------------------------------------------------------------------
// Kernel 1: build bf16 B-matrix [M][KPAD]:
//   [0,1024)   : C_m[d][f] = sum_e G[d][e]G[f][e]
//   [1024,1056): -2 * (C_m mu_m)[d]
//   1056,1057  : c = mu^T C mu split into bf16 hi + lo
//   [1058,1088): 0
// ---------------------------------------------------------------------------
__global__ __launch_bounds__(256) void build_b_kernel(
    const float* __restrict__ gamma, const float* __restrict__ means,
    unsigned short* __restrict__ Bm) {
  __shared__ float G[DDIM][DDIM + 1];
  __shared__ float C[DDIM][DDIM + 1];
  __shared__ float bv[DDIM];
  const int m = blockIdx.x;
  const int t = threadIdx.x;
  const float* g = gamma + (size_t)m * DDIM * DDIM;
  for (int l = t; l < DDIM * DDIM; l += 256) G[l >> 5][l & 31] = g[l];
  __syncthreads();
  const float* mu = means + m * DDIM;
  unsigned short* brow = Bm + (size_t)m * KPAD;
  for (int l = t; l < DDIM * DDIM; l += 256) {
    int d = l >> 5, f = l & 31;
    float c = 0.f;
#pragma unroll
    for (int e = 0; e < DDIM; ++e) c += G[d][e] * G[f][e];
    C[d][f] = c;
    brow[l] = (unsigned short)to_bf16(c);
  }
  __syncthreads();
  if (t < DDIM) {
    float b = 0.f;
#pragma unroll
    for (int f = 0; f < DDIM; ++f) b += C[t][f] * mu[f];
    bv[t] = b;
    brow[1024 + t] = (unsigned short)to_bf16(-2.f * b);
  } else if (t >= 64 && t < 94) {
    brow[1058 + (t - 64)] = 0;                       // zero pad
  }
  __syncthreads();
  if (t == 0) {
    float c = 0.f;
#pragma unroll
    for (int d = 0; d < DDIM; ++d) c += bv[d] * mu[d];
    unsigned int hi = to_bf16(c);
    union { unsigned int u; float f; } xh; xh.u = hi << 16;
    brow[1056] = (unsigned short)hi;
    brow[1057] = (unsigned short)to_bf16(c - xh.f);  // hi/lo split: |err| ~ 2^-17 rel
  }
}

// ---------------------------------------------------------------------------
// Exact path for rare survivors: D = ||G^T (x - mu)||^2 in fp32 (no cancellation),
// contribution accumulated in double. noinline: single code copy for 64 call sites.
// ---------------------------------------------------------------------------
__device__ __noinline__ double survivor_contrib(
    int m, const float* __restrict__ gamma, const float* __restrict__ means,
    const float* __restrict__ weights, const float* xrow) {
  const float* mu = means + m * DDIM;
  float v[DDIM];
#pragma unroll
  for (int d = 0; d < DDIM; ++d) v[d] = xrow[d] - mu[d];
  const float* g = gamma + (size_t)m * DDIM * DDIM;
  float Dex = 0.f;
  for (int e = 0; e < DDIM; ++e) {   // y_e = sum_d G[d][e] v[d]
    float y = 0.f;
#pragma unroll
    for (int d = 0; d < DDIM; ++d) y += g[d * DDIM + e] * v[d];
    Dex += y * y;
  }
  return (double)weights[m] * exp(-(double)Dex);
}

// ---------------------------------------------------------------------------
// Kernel 2: 128x128-tile bf16 MFMA screen GEMM, A generated on the fly from x.
// Layout (verified m89/m97): A/B frag = [row=lane&15][k=quad*8+j] via ds_read_b128;
// C/D: col(m)=lane&15, row(i)=quad*4+reg.
// ---------------------------------------------------------------------------
__global__ __launch_bounds__(256, 2) void screen_kernel(
    const float* __restrict__ x, const float* __restrict__ gamma,
    const float* __restrict__ means, const float* __restrict__ weights,
    const unsigned short* __restrict__ Bm, double* __restrict__ acc_out) {
  __shared__ float xs[128][36];                      // fp32 x-tile, 16B-aligned rows
  __shared__ unsigned short As[128 * ASTRIDE];
  __shared__ unsigned short Bs[128 * ASTRIDE];       // transposed: Bs[n][k]
  const int t = threadIdx.x;
  const int i0 = blockIdx.y * 128;
  const int m0 = blockIdx.x * 128;
  const int lane = t & 63, w = t >> 6;
  const int wm = w >> 1, wn = w & 1;
  const int lrow = lane & 15, quad = lane >> 4;

  // stage x tile (128 rows x 32 fp32)
#pragma unroll
  for (int it = 0; it < 4; ++it) {
    int l = it * 256 + t;
    int r = l >> 3, q = l & 7;
    floatx4 v = *(const floatx4*)(x + (size_t)(i0 + r) * DDIM + q * 4);
    *(floatx4*)&xs[r][q * 4] = v;
  }
  __syncthreads();

  floatx4 acc[4][4] = {};

  const int arow = t >> 1, dh = t & 1;               // A-gen strip: row, col-half
  unsigned short* adst = &As[arow * ASTRIDE + dh * 32];

  for (int kc = 0; kc < 17; ++kc) {
    const int k0 = kc * 64;
    // ---- generate A chunk: A[i][k] ----
    if (kc < 16) {                                   // k<1024: x_d * x_f
      const float xd = xs[arow][kc * 2 + dh];
#pragma unroll
      for (int q = 0; q < 4; ++q) {
        floatx4 a = *(const floatx4*)&xs[arow][q * 8];
        floatx4 b = *(const floatx4*)&xs[arow][q * 8 + 4];
        uint4 o;
        o.x = to_bf16(xd * a.x) | (to_bf16(xd * a.y) << 16);
        o.y = to_bf16(xd * a.z) | (to_bf16(xd * a.w) << 16);
        o.z = to_bf16(xd * b.x) | (to_bf16(xd * b.y) << 16);
        o.w = to_bf16(xd * b.z) | (to_bf16(xd * b.w) << 16);
        *(uint4*)(adst + q * 8) = o;
      }
    } else if (dh == 0) {                            // k in [1024,1056): x_f
#pragma unroll
      for (int q = 0; q < 4; ++q) {
        floatx4 a = *(const floatx4*)&xs[arow][q * 8];
        floatx4 b = *(const floatx4*)&xs[arow][q * 8 + 4];
        uint4 o;
        o.x = to_bf16(a.x) | (to_bf16(a.y) << 16);
        o.y = to_bf16(a.z) | (to_bf16(a.w) << 16);
        o.z = to_bf16(b.x) | (to_bf16(b.y) << 16);
        o.w = to_bf16(b.z) | (to_bf16(b.w) << 16);
        *(uint4*)(adst + q * 8) = o;
      }
    } else {                                         // k 1056,1057 = 1.0; rest 0
      uint4 o; o.x = 0x3f803f80u; o.y = 0u; o.z = 0u; o.w = 0u;
      *(uint4*)(adst) = o;
      uint4 z; z.x = z.y = z.z = z.w = 0u;
      *(uint4*)(adst + 8) = z;
      *(uint4*)(adst + 16) = z;
      *(uint4*)(adst + 24) = z;
    }
    // ---- stage B chunk transposed: Bs[n][k] = Bm[m0+n][k0+k] ----
#pragma unroll
    for (int it = 0; it < 4; ++it) {
      int l = it * 256 + t;
      int n = l >> 3, kq = l & 7;
      uint4 v = *(const uint4*)(Bm + (size_t)(m0 + n) * KPAD + k0 + kq * 8);
      *(uint4*)&Bs[n * ASTRIDE + kq * 8] = v;
    }
    __syncthreads();
    // ---- MFMA: 2 k-steps of 32, 4x4 tiles of 16x16 per wave ----
#pragma unroll
    for (int kk = 0; kk < 2; ++kk) {
      short8 af[4], bfv[4];
#pragma unroll
      for (int ti = 0; ti < 4; ++ti)
        af[ti] = *(const short8*)&As[(wm * 64 + ti * 16 + lrow) * ASTRIDE + kk * 32 + quad * 8];
#pragma unroll
      for (int tj = 0; tj < 4; ++tj)
        bfv[tj] = *(const short8*)&Bs[(wn * 64 + tj * 16 + lrow) * ASTRIDE + kk * 32 + quad * 8];
#pragma unroll
      for (int ti = 0; ti < 4; ++ti)
#pragma unroll
        for (int tj = 0; tj < 4; ++tj)
          acc[ti][tj] = __builtin_amdgcn_mfma_f32_16x16x32_bf16(
              af[ti], bfv[tj], acc[ti][tj], 0, 0, 0);
    }
    __syncthreads();
  }

  // ---- epilogue: screen, exact-recompute survivors ----
#pragma unroll
  for (int ti = 0; ti < 4; ++ti) {
#pragma unroll
    for (int tj = 0; tj < 4; ++tj) {
#pragma unroll
      for (int r = 0; r < 4; ++r) {
        float Dt = acc[ti][tj][r];
        if (Dt < SCREEN) {
          int il = wm * 64 + ti * 16 + quad * 4 + r;
          int ml = wn * 64 + tj * 16 + lrow;
          double c = survivor_contrib(m0 + ml, gamma, means, weights,
                                      (const float*)&xs[il][0]);
          atomicAdd(&acc_out[i0 + il], c);
        }
      }
    }
  }
}

__global__ __launch_bounds__(256) void finalize_kernel(
    const double* __restrict__ acc, float* __restrict__ out) {
  int i = blockIdx.x * 256 + threadIdx.x;
  out[i] = (float)acc[i];
}

extern "C" void kernel_launch(void* const* d_in, const int* in_sizes, int n_in,
                              void* d_out, int out_size, void* d_ws, size_t ws_size,
                              hipStream_t stream) {
  (void)in_sizes; (void)n_in; (void)out_size;
  const float* x       = (const float*)d_in[0];   // [N][32]
  const float* gamma   = (const float*)d_in[1];   // [M][32][32]
  const float* means   = (const float*)d_in[2];   // [M][32]
  const float* weights = (const float*)d_in[3];   // [M]
  double* acc = (double*)d_ws;                                        // [N] doubles
  unsigned short* Bm = (unsigned short*)((char*)d_ws + (size_t)NN * 8); // [M][KPAD] bf16
  size_t needed = (size_t)NN * 8 + (size_t)MM * KPAD * 2;
  if (ws_size < needed) return;  // fail loudly via validation rather than corrupt

  hipMemsetAsync(d_ws, 0, (size_t)NN * 8, stream);
  hipLaunchKernelGGL(build_b_kernel, dim3(MM), dim3(256), 0, stream, gamma, means, Bm);
  hipLaunchKernelGGL(screen_kernel, dim3(MM / 128, NN / 128), dim3(256), 0, stream,
                     x, gamma, means, weights, Bm, acc);
  hipLaunchKernelGGL(finalize_kernel, dim3(NN / 256), dim3(256), 0, stream,
                     acc, (float*)d_out);
}

// Round 3
// 818.704 us; speedup vs baseline: 1.0178x; 1.0178x over previous
//
#include <hip/hip_runtime.h>
#include <math.h>

// RBF mixture: out[i] = sum_m w_m * exp(-(x_i-mu_m)^T C_m (x_i-mu_m)), C_m = G_m G_m^T
// N=32768, M=2048, D=32.
// Round 3: identical to round 2 except the epilogue survivor write/read now
// includes the block-tile base i0 (round-2 bug: acc_out[il] / xc+il*DDIM
// dropped i0 -> output zeros everywhere except chunk rows [0,128)).

#define NN 32768
#define MM 2048
#define DDIM 32
#define KPAD 1088          // 17 * 64
#define SCREEN 256.0f

typedef __attribute__((ext_vector_type(8))) short short8;
typedef __attribute__((ext_vector_type(4))) float floatx4;

__device__ __forceinline__ unsigned int to_bf16(float f) {
  union { float f; unsigned int u; } x; x.f = f;
  return (x.u + 0x7fffu + ((x.u >> 16) & 1u)) >> 16;   // RNE, finite inputs only
}

// ---------------------------------------------------------------------------
// Kernel 1: build bf16 B-matrix [M][KPAD]:
//   [0,1024): C_m flat; [1024,1056): -2*C_m mu; 1056/1057: mu^T C mu hi/lo; pad 0
// ---------------------------------------------------------------------------
__global__ __launch_bounds__(256) void build_b_kernel(
    const float* __restrict__ gamma, const float* __restrict__ means,
    unsigned short* __restrict__ Bm) {
  __shared__ float G[DDIM][DDIM + 1];
  __shared__ float C[DDIM][DDIM + 1];
  __shared__ float bv[DDIM];
  const int m = blockIdx.x;
  const int t = threadIdx.x;
  const float* g = gamma + (size_t)m * DDIM * DDIM;
  for (int l = t; l < DDIM * DDIM; l += 256) G[l >> 5][l & 31] = g[l];
  __syncthreads();
  const float* mu = means + m * DDIM;
  unsigned short* brow = Bm + (size_t)m * KPAD;
  for (int l = t; l < DDIM * DDIM; l += 256) {
    int d = l >> 5, f = l & 31;
    float c = 0.f;
#pragma unroll
    for (int e = 0; e < DDIM; ++e) c += G[d][e] * G[f][e];
    C[d][f] = c;
    brow[l] = (unsigned short)to_bf16(c);
  }
  __syncthreads();
  if (t < DDIM) {
    float b = 0.f;
#pragma unroll
    for (int f = 0; f < DDIM; ++f) b += C[t][f] * mu[f];
    bv[t] = b;
    brow[1024 + t] = (unsigned short)to_bf16(-2.f * b);
  } else if (t >= 64 && t < 94) {
    brow[1058 + (t - 64)] = 0;
  }
  __syncthreads();
  if (t == 0) {
    float c = 0.f;
#pragma unroll
    for (int d = 0; d < DDIM; ++d) c += bv[d] * mu[d];
    unsigned int hi = to_bf16(c);
    union { unsigned int u; float f; } xh; xh.u = hi << 16;
    brow[1056] = (unsigned short)hi;
    brow[1057] = (unsigned short)to_bf16(c - xh.f);
  }
}

// ---------------------------------------------------------------------------
// Kernel 2: build bf16 A-matrix chunk [rows][KPAD]:
//   [0,1024): x_d*x_f; [1024,1056): x_f; 1056,1057: 1.0; pad 0
// 32 rows/block, 8 threads/row (thread j covers d = 4j..4j+3).
// ---------------------------------------------------------------------------
__global__ __launch_bounds__(256) void build_a_kernel(
    const float* __restrict__ x, unsigned short* __restrict__ Am) {
  __shared__ float xs[32][32];
  const int t = threadIdx.x;
  const int r0 = blockIdx.x * 32;
  {
    int r = t >> 3, q = t & 7;
    floatx4 v = *(const floatx4*)(x + (size_t)(r0 + r) * DDIM + q * 4);
    *(floatx4*)&xs[r][q * 4] = v;
  }
  __syncthreads();
  const int r = t >> 3, j = t & 7;
  unsigned short* arow = Am + (size_t)(r0 + r) * KPAD;
#pragma unroll
  for (int dd = 0; dd < 4; ++dd) {
    int d = j * 4 + dd;
    float xd = xs[r][d];
#pragma unroll
    for (int q = 0; q < 4; ++q) {
      floatx4 a = *(const floatx4*)&xs[r][q * 8];
      floatx4 b = *(const floatx4*)&xs[r][q * 8 + 4];
      uint4 o;
      o.x = to_bf16(xd * a.x) | (to_bf16(xd * a.y) << 16);
      o.y = to_bf16(xd * a.z) | (to_bf16(xd * a.w) << 16);
      o.z = to_bf16(xd * b.x) | (to_bf16(xd * b.y) << 16);
      o.w = to_bf16(xd * b.z) | (to_bf16(xd * b.w) << 16);
      *(uint4*)(arow + d * 32 + q * 8) = o;
    }
  }
  if (j == 0) {   // tail: x | 1,1 | zeros
#pragma unroll
    for (int q = 0; q < 4; ++q) {
      floatx4 a = *(const floatx4*)&xs[r][q * 8];
      floatx4 b = *(const floatx4*)&xs[r][q * 8 + 4];
      uint4 o;
      o.x = to_bf16(a.x) | (to_bf16(a.y) << 16);
      o.y = to_bf16(a.z) | (to_bf16(a.w) << 16);
      o.z = to_bf16(b.x) | (to_bf16(b.y) << 16);
      o.w = to_bf16(b.z) | (to_bf16(b.w) << 16);
      *(uint4*)(arow + 1024 + q * 8) = o;
    }
    uint4 one; one.x = 0x3f803f80u; one.y = 0u; one.z = 0u; one.w = 0u;
    *(uint4*)(arow + 1056) = one;
    uint4 z; z.x = z.y = z.z = z.w = 0u;
    *(uint4*)(arow + 1064) = z;
    *(uint4*)(arow + 1072) = z;
    *(uint4*)(arow + 1080) = z;
  }
}

// ---------------------------------------------------------------------------
// Exact path for rare survivors (fp32, no cancellation; double accumulate).
// ---------------------------------------------------------------------------
__device__ __noinline__ double survivor_contrib(
    int m, const float* __restrict__ gamma, const float* __restrict__ means,
    const float* __restrict__ weights, const float* __restrict__ xrow) {
  const float* mu = means + m * DDIM;
  float v[DDIM];
#pragma unroll
  for (int d = 0; d < DDIM; ++d) v[d] = xrow[d] - mu[d];
  const float* g = gamma + (size_t)m * DDIM * DDIM;
  float Dex = 0.f;
  for (int e = 0; e < DDIM; ++e) {
    float y = 0.f;
#pragma unroll
    for (int d = 0; d < DDIM; ++d) y += g[d * DDIM + e] * v[d];
    Dex += y * y;
  }
  return (double)weights[m] * exp(-(double)Dex);
}

// ---------------------------------------------------------------------------
// Kernel 3: pure bf16 MFMA screen GEMM, 128x128 tile, BK=64, K=1088.
// global_load_lds width-16 staging; LDS rows 64 bf16 (128 B) with XOR chunk
// swizzle: chunk c of row r lives at slot c^(r&7) -> b128 reads hit all 32
// banks. Frag layout (m89/m97): A/B [row=lane&15][k=quad*8+j]; C/D
// col=lane&15, row=quad*4+reg.
// ---------------------------------------------------------------------------
__global__ __launch_bounds__(256) void screen_kernel(
    const unsigned short* __restrict__ Am, const float* __restrict__ xc,
    const float* __restrict__ gamma, const float* __restrict__ means,
    const float* __restrict__ weights, const unsigned short* __restrict__ Bm,
    double* __restrict__ acc_out) {
  __shared__ unsigned short As[128 * 64];
  __shared__ unsigned short Bs[128 * 64];
  const int t = threadIdx.x;
  const int i0 = blockIdx.y * 128;
  const int m0 = blockIdx.x * 128;
  const int lane = t & 63, w = t >> 6;
  const int wm = w >> 1, wn = w & 1;
  const int lrow = lane & 15, quad = lane >> 4;
  const int srow = lane >> 3, sslot = lane & 7;

  floatx4 acc[4][4] = {};

  for (int kc = 0; kc < 17; ++kc) {
#pragma unroll
    for (int p = 0; p < 4; ++p) {
      const int rb = p * 32 + w * 8;               // wave-uniform row base
      const int r = rb + srow;
      const int c = sslot ^ (r & 7);               // swizzled source chunk
      const unsigned short* gA = Am + (size_t)(i0 + r) * KPAD + kc * 64 + c * 8;
      const unsigned short* gB = Bm + (size_t)(m0 + r) * KPAD + kc * 64 + c * 8;
      __builtin_amdgcn_global_load_lds(
          (const __attribute__((address_space(1))) void*)gA,
          (__attribute__((address_space(3))) void*)(As + (size_t)rb * 64), 16, 0, 0);
      __builtin_amdgcn_global_load_lds(
          (const __attribute__((address_space(1))) void*)gB,
          (__attribute__((address_space(3))) void*)(Bs + (size_t)rb * 64), 16, 0, 0);
    }
    __syncthreads();
#pragma unroll
    for (int kk = 0; kk < 2; ++kk) {
      short8 af[4], bfv[4];
#pragma unroll
      for (int ti = 0; ti < 4; ++ti) {
        int ar = wm * 64 + ti * 16 + lrow;
        int slot = (kk * 4 + quad) ^ (ar & 7);
        af[ti] = *(const short8*)&As[ar * 64 + slot * 8];
      }
#pragma unroll
      for (int tj = 0; tj < 4; ++tj) {
        int br = wn * 64 + tj * 16 + lrow;
        int slot = (kk * 4 + quad) ^ (br & 7);
        bfv[tj] = *(const short8*)&Bs[br * 64 + slot * 8];
      }
#pragma unroll
      for (int ti = 0; ti < 4; ++ti)
#pragma unroll
        for (int tj = 0; tj < 4; ++tj)
          acc[ti][tj] = __builtin_amdgcn_mfma_f32_16x16x32_bf16(
              af[ti], bfv[tj], acc[ti][tj], 0, 0, 0);
    }
    __syncthreads();
  }

  // epilogue: screen, exact-recompute survivors (NOTE the i0 + il base!)
#pragma unroll
  for (int ti = 0; ti < 4; ++ti) {
#pragma unroll
    for (int tj = 0; tj < 4; ++tj) {
#pragma unroll
      for (int r = 0; r < 4; ++r) {
        float Dt = acc[ti][tj][r];
        if (Dt < SCREEN) {
          int il = wm * 64 + ti * 16 + quad * 4 + r;
          int ml = wn * 64 + tj * 16 + lrow;
          double c = survivor_contrib(m0 + ml, gamma, means, weights,
                                      xc + (size_t)(i0 + il) * DDIM);
          atomicAdd(&acc_out[i0 + il], c);
        }
      }
    }
  }
}

__global__ __launch_bounds__(256) void finalize_kernel(
    const double* __restrict__ acc, float* __restrict__ out) {
  int i = blockIdx.x * 256 + threadIdx.x;
  out[i] = (float)acc[i];
}

extern "C" void kernel_launch(void* const* d_in, const int* in_sizes, int n_in,
                              void* d_out, int out_size, void* d_ws, size_t ws_size,
                              hipStream_t stream) {
  (void)in_sizes; (void)n_in; (void)out_size;
  const float* x       = (const float*)d_in[0];   // [N][32]
  const float* gamma   = (const float*)d_in[1];   // [M][32][32]
  const float* means   = (const float*)d_in[2];   // [M][32]
  const float* weights = (const float*)d_in[3];   // [M]

  double* acc        = (double*)d_ws;                                     // [N]
  unsigned short* Bm = (unsigned short*)((char*)d_ws + (size_t)NN * 8);   // [M][KPAD]
  unsigned short* Am = (unsigned short*)((char*)Bm + (size_t)MM * KPAD * 2);
  const size_t fixed = (size_t)NN * 8 + (size_t)MM * KPAD * 2;
  if (ws_size < fixed + (size_t)128 * KPAD * 2) return;  // can't run at all

  size_t avail = ws_size - fixed;
  long rows_cap = (long)(avail / ((size_t)KPAD * 2));
  rows_cap = (rows_cap / 128) * 128;
  if (rows_cap > NN) rows_cap = NN;

  hipMemsetAsync(acc, 0, (size_t)NN * 8, stream);
  hipLaunchKernelGGL(build_b_kernel, dim3(MM), dim3(256), 0, stream, gamma, means, Bm);
  for (long i0 = 0; i0 < NN; i0 += rows_cap) {
    long rows = (NN - i0 < rows_cap) ? (NN - i0) : rows_cap;
    hipLaunchKernelGGL(build_a_kernel, dim3(rows / 32), dim3(256), 0, stream,
                       x + (size_t)i0 * DDIM, Am);
    hipLaunchKernelGGL(screen_kernel, dim3(MM / 128, rows / 128), dim3(256), 0, stream,
                       Am, x + (size_t)i0 * DDIM, gamma, means, weights, Bm,
                       acc + i0);
  }
  hipLaunchKernelGGL(finalize_kernel, dim3(NN / 256), dim3(256), 0, stream,
                     acc, (float*)d_out);
}